// Round 10
// baseline (3807.715 us; speedup 1.0000x reference)
//
#include <hip/hip_runtime.h>
#include <stdint.h>

#define BB      128
#define DIN     512
#define DMODEL  2048
#define MEMN    25
#define NSY     256
#define OUTD    1000
#define ITERS   24
#define SYNCN   32896
#define KPAD    33792      // 66 * 512 = 32 * 1056
#define NPAD    1024
#define PREDTOT (BB*OUTD*ITERS)

typedef __attribute__((ext_vector_type(8))) short bf16x8;
typedef __attribute__((ext_vector_type(4))) float f32x4;

__device__ __forceinline__ unsigned short f2bf(float x){
    unsigned int u = __float_as_uint(x);
    u += 0x7fffu + ((u >> 16) & 1u);
    return (unsigned short)(u >> 16);
}
__device__ __forceinline__ float bf2f(unsigned short h){
    unsigned int u = ((unsigned int)h) << 16;
    return __uint_as_float(u);
}
__device__ __forceinline__ float sigm(float x){ return 1.f/(1.f + __expf(-x)); }

// async global->LDS, 16B per lane; LDS dest is wave-uniform base + lane*16
__device__ __forceinline__ void gload16(const unsigned short* g, unsigned short* l){
    __builtin_amdgcn_global_load_lds(
        (const __attribute__((address_space(1))) unsigned int*)(const void*)g,
        (__attribute__((address_space(3))) unsigned int*)(void*)l,
        16, 0, 0);
}

// 256-thread reduce+softmax+entropy for one batch row b at iteration t.
// red = 8-float shared scratch. Writes dout directly (final layout).
__device__ __forceinline__ void reduce_row(const float* __restrict__ part, const float* __restrict__ outb,
    float* __restrict__ dout, float* red, int b, int t, int tid, int nsplit){
    float v[4];
    float m = -1e30f;
#pragma unroll
    for (int q = 0; q < 4; ++q){
        int n = q*256 + tid;
        float s;
        if (n < OUTD){
            s = outb[n];
            for (int sk = 0; sk < nsplit; ++sk)
                s += part[(long)sk*(BB*NPAD) + (long)b*NPAD + n];
        } else s = -1e30f;
        v[q] = s;
        m = fmaxf(m, s);
    }
#pragma unroll
    for (int off = 32; off; off >>= 1) m = fmaxf(m, __shfl_down(m, off));
    int w = tid >> 6;
    if ((tid & 63) == 0) red[w] = m;
    __syncthreads();
    float M = fmaxf(fmaxf(red[0], red[1]), fmaxf(red[2], red[3]));
    __syncthreads();
    float z = 0.f, s2 = 0.f;
#pragma unroll
    for (int q = 0; q < 4; ++q){
        int n = q*256 + tid;
        if (n < OUTD){
            float e = __expf(v[q] - M);
            z += e; s2 += e*v[q];
        }
    }
#pragma unroll
    for (int off = 32; off; off >>= 1){
        z  += __shfl_down(z, off);
        s2 += __shfl_down(s2, off);
    }
    if ((tid & 63) == 0){ red[w] = z; red[4+w] = s2; }
    __syncthreads();
    if (tid == 0){
        float Z = red[0]+red[1]+red[2]+red[3];
        float S = red[4]+red[5]+red[6]+red[7];
        float logZ = M + __logf(Z);
        float ne = (logZ - S/Z) / 6.907755278982137f;
        dout[PREDTOT + b*48 + t] = ne;
        dout[PREDTOT + b*48 + 24 + t] = 1.f - ne;
    }
#pragma unroll
    for (int q = 0; q < 4; ++q){
        int n = q*256 + tid;
        if (n < OUTD) dout[(long)b*(OUTD*ITERS) + (long)n*ITERS + t] = v[q];
    }
}

// ---------------- init kernels (run every launch: ws is re-poisoned) ----------------

__global__ __launch_bounds__(256) void init_trace_k(const float* __restrict__ st,
    unsigned short* __restrict__ trh, unsigned short* __restrict__ trl){
    const long N = (long)MEMN*DMODEL*BB;
    for (long i = (long)blockIdx.x*256 + threadIdx.x; i < N; i += (long)gridDim.x*256){
        int m = (int)(i / (DMODEL*BB));
        int rem = (int)(i % (DMODEL*BB));
        int d = rem >> 7;
        float v = st[d*MEMN + m];
        unsigned short h = f2bf(v);
        trh[i] = h;
        trl[i] = f2bf(v - bf2f(h));
    }
}

__global__ __launch_bounds__(256) void init_act_k(const float* __restrict__ sas, float* __restrict__ act){
    for (int i = blockIdx.x*256 + threadIdx.x; i < DMODEL*BB; i += gridDim.x*256)
        act[i] = sas[i >> 7];
}

__global__ __launch_bounds__(256) void init_alpha_k(const float* __restrict__ sas,
    const int* __restrict__ il, const int* __restrict__ ir, float* __restrict__ alpha){
    int i = blockIdx.x, tid = threadIdx.x;
    if (tid >= NSY - i) return;
    int j = i + tid;
    int k = i*(2*NSY - i + 1)/2 + tid;
    float a0 = sas[il[i]] * sas[ir[j]];
    for (int b = 0; b < BB; ++b) alpha[b*SYNCN + k] = a0;
}

__global__ __launch_bounds__(256) void init_rowmap_k(int* __restrict__ rowOf, int* __restrict__ rowstart){
    int i = blockIdx.x, tid = threadIdx.x;
    int start = i*(2*NSY - i + 1)/2;
    int len = NSY - i;
    if (tid == 0) rowstart[i] = start;
    for (int t = tid; t < len; t += 256) rowOf[start + t] = i;
}

__global__ __launch_bounds__(256) void transpose_f32_k(const float* __restrict__ in, float* __restrict__ out, int R, int C){
    __shared__ float S[64][65];
    int r0 = blockIdx.y*64, c0 = blockIdx.x*64;
    for (int i = threadIdx.x; i < 64*64; i += 256){
        int rr = i >> 6, cc = i & 63;
        int r = r0+rr, c = c0+cc;
        if (r < R && c < C) S[rr][cc] = in[(long)r*C + c];
    }
    __syncthreads();
    for (int i = threadIdx.x; i < 64*64; i += 256){
        int cc = i >> 6, rr = i & 63;
        int r = r0+rr, c = c0+cc;
        if (r < R && c < C) out[(long)c*R + r] = S[rr][cc];
    }
}

// w1t [d][m*64+h] f32 -> w1bf [d][plane(hi=0,lo=1)][h*32+m] bf16, m padded 25->32 with zeros
__global__ __launch_bounds__(256) void w1bf_prep_k(const float* __restrict__ w1t, unsigned short* __restrict__ w1bf){
    int d = blockIdx.x, tid = threadIdx.x;
    __shared__ float S[1600];
    for (int i = tid; i < 1600; i += 256) S[i] = w1t[(long)d*1600 + i];
    __syncthreads();
    for (int i = tid; i < 2048; i += 256){
        int h = i >> 5, m = i & 31;
        float v = (m < MEMN) ? S[m*64 + h] : 0.f;
        unsigned short hi = f2bf(v);
        unsigned short lo = f2bf(v - bf2f(hi));
        w1bf[(long)d*4096 + i]        = hi;
        w1bf[(long)d*4096 + 2048 + i] = lo;
    }
}

// out_w f32 [SYNCN][OUTD] -> bf16 [NPAD][KPAD] (transposed); 64x64 tiles
__global__ __launch_bounds__(256) void wbf_transpose_k(const float* __restrict__ w, unsigned short* __restrict__ wt){
    __shared__ float S[64][65];
    int k0 = blockIdx.x*64, n0 = blockIdx.y*64;
    int tid = threadIdx.x;
    if (k0 >= SYNCN){
        uint4 z = {0u,0u,0u,0u};
#pragma unroll
        for (int p = 0; p < 2; ++p){
            int i = tid + p*256;
            int nn = i >> 3, k8 = (i & 7)*8;
            *(uint4*)(wt + (long)(n0+nn)*KPAD + k0 + k8) = z;
        }
        return;
    }
    const long MAXI = (long)SYNCN*OUTD - 4;
#pragma unroll
    for (int p = 0; p < 4; ++p){
        int i = tid + p*256;
        int rr = i >> 4, c4 = (i & 15)*4;
        long idx = (long)(k0+rr)*OUTD + n0 + c4;
        if (idx > MAXI) idx = MAXI;
        float4 v = *(const float4*)(w + idx);
        S[rr][c4+0]=v.x; S[rr][c4+1]=v.y; S[rr][c4+2]=v.z; S[rr][c4+3]=v.w;
    }
    __syncthreads();
#pragma unroll
    for (int p = 0; p < 4; ++p){
        int i = tid + p*256;
        int nn = i >> 4, k4 = (i & 15)*4;
        ushort4 o;
        o.x = f2bf(S[k4+0][nn]); o.y = f2bf(S[k4+1][nn]);
        o.z = f2bf(S[k4+2][nn]); o.w = f2bf(S[k4+3][nn]);
        *(ushort4*)(wt + (long)(n0+nn)*KPAD + k0 + k4) = o;
    }
}

// syn_w rows [512..2560) f32 [k][4096] -> swT hi/lo bf16 [n=4096][k=2048]; 64x64 tiles
__global__ __launch_bounds__(256) void swt_convert_k(const float* __restrict__ w,
    unsigned short* __restrict__ th, unsigned short* __restrict__ tl){
    __shared__ float S[64][65];
    int k0 = blockIdx.x*64, n0 = blockIdx.y*64;
    int tid = threadIdx.x;
#pragma unroll
    for (int p = 0; p < 4; ++p){
        int i = tid + p*256;
        int rr = i >> 4, c4 = (i & 15)*4;
        float4 v = *(const float4*)(w + (long)(512 + k0 + rr)*4096 + n0 + c4);
        S[rr][c4+0]=v.x; S[rr][c4+1]=v.y; S[rr][c4+2]=v.z; S[rr][c4+3]=v.w;
    }
    __syncthreads();
#pragma unroll
    for (int p = 0; p < 4; ++p){
        int i = tid + p*256;
        int nn = i >> 4, k4 = (i & 15)*4;
        ushort4 oh, ol;
        float v0 = S[k4+0][nn], v1 = S[k4+1][nn], v2 = S[k4+2][nn], v3 = S[k4+3][nn];
        oh.x = f2bf(v0); oh.y = f2bf(v1); oh.z = f2bf(v2); oh.w = f2bf(v3);
        ol.x = f2bf(v0 - bf2f(oh.x)); ol.y = f2bf(v1 - bf2f(oh.y));
        ol.z = f2bf(v2 - bf2f(oh.z)); ol.w = f2bf(v3 - bf2f(oh.w));
        *(ushort4*)(th + (long)(n0+nn)*DMODEL + k0 + k4) = oh;
        *(ushort4*)(tl + (long)(n0+nn)*DMODEL + k0 + k4) = ol;
    }
}

// act [d=2048][b=128] f32 -> aT hi/lo bf16 [b][d]  (init only)
__global__ __launch_bounds__(256) void act_convert_k(const float* __restrict__ act,
    unsigned short* __restrict__ th, unsigned short* __restrict__ tl){
    __shared__ float S[64][65];
    int d0 = blockIdx.x*64, b0 = blockIdx.y*64;
    int tid = threadIdx.x;
#pragma unroll
    for (int p = 0; p < 4; ++p){
        int i = tid + p*256;
        int rr = i >> 4, c4 = (i & 15)*4;
        float4 v = *(const float4*)(act + (long)(d0+rr)*BB + b0 + c4);
        S[rr][c4+0]=v.x; S[rr][c4+1]=v.y; S[rr][c4+2]=v.z; S[rr][c4+3]=v.w;
    }
    __syncthreads();
#pragma unroll
    for (int p = 0; p < 4; ++p){
        int i = tid + p*256;
        int nn = i >> 4, k4 = (i & 15)*4;
        unsigned short h[4], l[4];
#pragma unroll
        for (int q = 0; q < 4; ++q){
            float v = S[k4+q][nn];
            h[q] = f2bf(v);
            l[q] = f2bf(v - bf2f(h[q]));
        }
        *(ushort4*)(th + (long)(b0+nn)*DMODEL + d0 + k4) = ushort4{h[0],h[1],h[2],h[3]};
        *(ushort4*)(tl + (long)(b0+nn)*DMODEL + d0 + k4) = ushort4{l[0],l[1],l[2],l[3]};
    }
}

// fp32 GEMM (once, for C0): out[b][j](4096) = bias + sum_k A[k][b]*Bw[k][j], K=512
__global__ __launch_bounds__(256) void gemm_syn_k(const float* __restrict__ A, const float* __restrict__ Bw,
    const float* __restrict__ bias, float* __restrict__ out){
    int j_base = blockIdx.x*64;
    int tid = threadIdx.x;
    __shared__ float As[16][128];
    __shared__ float Bs[16][68];
    int bg = tid & 15, jg = tid >> 4;
    int b0 = bg*8, j0 = jg*4;
    float acc[8][4];
#pragma unroll
    for (int i = 0; i < 8; ++i)
#pragma unroll
        for (int q = 0; q < 4; ++q) acc[i][q] = 0.f;
    for (int kt = 0; kt < 32; ++kt){
        {
            int i0 = tid*8;
            int kk = i0 >> 7, bb = i0 & 127;
            const float4* src = (const float4*)(A + (long)(kt*16+kk)*BB + bb);
            float4 v0 = src[0], v1 = src[1];
            *(float4*)&As[kk][bb]   = v0;
            *(float4*)&As[kk][bb+4] = v1;
        }
        {
            int i0 = tid*4;
            int kk = i0 >> 6, jj = i0 & 63;
            float4 v = *(const float4*)(Bw + (long)(kt*16+kk)*4096 + j_base + jj);
            *(float4*)&Bs[kk][jj] = v;
        }
        __syncthreads();
#pragma unroll
        for (int kk = 0; kk < 16; ++kk){
            float a[8], bv[4];
            *(float4*)&a[0] = *(float4*)&As[kk][b0];
            *(float4*)&a[4] = *(float4*)&As[kk][b0+4];
            *(float4*)&bv[0] = *(float4*)&Bs[kk][j0];
#pragma unroll
            for (int i = 0; i < 8; ++i)
#pragma unroll
                for (int q = 0; q < 4; ++q) acc[i][q] += a[i]*bv[q];
        }
        __syncthreads();
    }
#pragma unroll
    for (int i = 0; i < 8; ++i){
        int bb = b0 + i;
        float4 v;
        v.x = acc[i][0]+bias[j_base+j0+0]; v.y = acc[i][1]+bias[j_base+j0+1];
        v.z = acc[i][2]+bias[j_base+j0+2]; v.w = acc[i][3]+bias[j_base+j0+3];
        *(float4*)(out + (long)bb*4096 + j_base + j0) = v;
    }
}

// ---------------- per-iteration fused dispatches ----------------
// D1(t): out(t-1) [blocks 0..16*nsO) ∥ glu(t) [next 128 blocks]; 256 threads
// out: single-panel staging (R7-proven), runtime split count nsO, KCHo = KPAD/nsO
__global__ __launch_bounds__(256) void d1_out_glu_k(
    const unsigned short* __restrict__ Abf, const unsigned short* __restrict__ Bbf,
    float* __restrict__ part,
    const float* __restrict__ C0, const float* __restrict__ zp,
    const float* __restrict__ lng, const float* __restrict__ lnb,
    unsigned short* __restrict__ trh, unsigned short* __restrict__ trl,
    int slot, int do_out, int nsO, int KCHo, int nsS){
    __shared__ __align__(16) char U[24576];
    int tid = threadIdx.x;
    int bid = blockIdx.x;
    if (bid < 16*nsO){
        // ---- out_gemm(t-1): part[sk][128][NPAD] = sync @ wt^T ----
        if (!do_out) return;
        unsigned short* As = (unsigned short*)U;           // 128*32 = 8192 B
        unsigned short* Bs = (unsigned short*)(U + 8192);  // 64*32  = 4096 B
        int wid = tid >> 6, lane = tid & 63;
        int wm = (wid & 1)*64, wn = (wid >> 1)*32;
        int mrow = lane & 15, kq = lane >> 4;
        int srow = tid >> 2;
        int ksg  = (tid & 3)*8;
        int sk = bid >> 4;
        int n_base = (bid & 15)*64;
        long k_base = (long)sk*KCHo;

        f32x4 c[4][2];
#pragma unroll
        for (int a = 0; a < 4; ++a)
#pragma unroll
            for (int b = 0; b < 2; ++b) c[a][b] = (f32x4){0.f,0.f,0.f,0.f};

        const unsigned short* gA1 = Abf + (long)srow*KPAD      + k_base + ksg;
        const unsigned short* gA2 = Abf + (long)(srow+64)*KPAD + k_base + ksg;
        const unsigned short* gB  = Bbf + (long)(n_base+srow)*KPAD + k_base + ksg;
        unsigned short* lA1 = As + wid*512;
        unsigned short* lA2 = As + 2048 + wid*512;
        unsigned short* lB  = Bs + wid*512;

        int NS = KCHo >> 5;
        for (int ks = 0; ks < NS; ++ks){
            int o = ks*32;
            gload16(gA1 + o, lA1);
            gload16(gA2 + o, lA2);
            gload16(gB  + o, lB);
            __syncthreads();
            bf16x8 af[4], bf[2];
#pragma unroll
            for (int x = 0; x < 4; ++x)
                af[x] = *(const bf16x8*)&As[(wm + x*16 + mrow)*32 + kq*8];
#pragma unroll
            for (int y = 0; y < 2; ++y)
                bf[y] = *(const bf16x8*)&Bs[(wn + y*16 + mrow)*32 + kq*8];
#pragma unroll
            for (int a = 0; a < 4; ++a)
#pragma unroll
                for (int b = 0; b < 2; ++b)
                    c[a][b] = __builtin_amdgcn_mfma_f32_16x16x32_bf16(af[a], bf[b], c[a][b], 0, 0, 0);
            __syncthreads();
        }
        float* outp = part + (long)sk*(128*NPAD);
#pragma unroll
        for (int a = 0; a < 4; ++a)
#pragma unroll
            for (int b = 0; b < 2; ++b){
                int r0 = wm + a*16 + (lane >> 4)*4;
                int col = n_base + wn + b*16 + (lane & 15);
#pragma unroll
                for (int reg = 0; reg < 4; ++reg)
                    outp[(long)(r0+reg)*NPAD + col] = c[a][b][reg];
            }
    } else {
        // ---- GLU + LayerNorm (256 threads, 8 dims/thread), sums nsS zpart splits ----
        float* redA = (float*)U;          // 4 floats
        float* redB = (float*)(U + 16);   // 4 floats
        int b = bid - 16*nsO;
        int d0 = tid*8;
        const float* base = C0 + (long)b*4096;
        float4 a0 = *(const float4*)(base + d0);
        float4 a1 = *(const float4*)(base + d0 + 4);
        float4 g0 = *(const float4*)(base + 2048 + d0);
        float4 g1 = *(const float4*)(base + 2048 + d0 + 4);
        for (int s = 0; s < nsS; ++s){
            const float* zb = zp + (long)s*524288 + (long)b*4096;
            float4 z0 = *(const float4*)(zb + d0);
            float4 z1 = *(const float4*)(zb + d0 + 4);
            float4 y0 = *(const float4*)(zb + 2048 + d0);
            float4 y1 = *(const float4*)(zb + 2048 + d0 + 4);
            a0.x+=z0.x; a0.y+=z0.y; a0.z+=z0.z; a0.w+=z0.w;
            a1.x+=z1.x; a1.y+=z1.y; a1.z+=z1.z; a1.w+=z1.w;
            g0.x+=y0.x; g0.y+=y0.y; g0.z+=y0.z; g0.w+=y0.w;
            g1.x+=y1.x; g1.y+=y1.y; g1.z+=y1.z; g1.w+=y1.w;
        }
        float v[8];
        v[0]=a0.x*sigm(g0.x); v[1]=a0.y*sigm(g0.y); v[2]=a0.z*sigm(g0.z); v[3]=a0.w*sigm(g0.w);
        v[4]=a1.x*sigm(g1.x); v[5]=a1.y*sigm(g1.y); v[6]=a1.z*sigm(g1.z); v[7]=a1.w*sigm(g1.w);
        float s1 = 0.f, s2 = 0.f;
#pragma unroll
        for (int i = 0; i < 8; ++i){ s1 += v[i]; s2 += v[i]*v[i]; }
#pragma unroll
        for (int off = 32; off; off >>= 1){
            s1 += __shfl_down(s1, off);
            s2 += __shfl_down(s2, off);
        }
        int w = tid >> 6;
        if ((tid & 63) == 0){ redA[w] = s1; redB[w] = s2; }
        __syncthreads();
        if (tid == 0){
            float sa = redA[0]+redA[1]+redA[2]+redA[3];
            float sb = redB[0]+redB[1]+redB[2]+redB[3];
            float mu = sa*(1.f/2048.f);
            float var = sb*(1.f/2048.f) - mu*mu;
            redA[0] = mu;
            redB[0] = rsqrtf(var + 1e-5f);
        }
        __syncthreads();
        float mu = redA[0], inv = redB[0];
        float4 lg0 = *(const float4*)(lng + d0);
        float4 lg1 = *(const float4*)(lng + d0 + 4);
        float4 lb0 = *(const float4*)(lnb + d0);
        float4 lb1 = *(const float4*)(lnb + d0 + 4);
        float gg[8] = {lg0.x,lg0.y,lg0.z,lg0.w,lg1.x,lg1.y,lg1.z,lg1.w};
        float bb[8] = {lb0.x,lb0.y,lb0.z,lb0.w,lb1.x,lb1.y,lb1.z,lb1.w};
        long obase = ((long)slot*DMODEL + d0)*BB + b;
#pragma unroll
        for (int i = 0; i < 8; ++i){
            float st = (v[i]-mu)*inv*gg[i] + bb[i];
            unsigned short h = f2bf(st);
            trh[obase + (long)i*BB] = h;
            trl[obase + (long)i*BB] = f2bf(st - bf2f(h));
        }
    }
}

// D2(t): reduce(t-1) [blocks 0..127] ∥ trace(t) [blocks 128..2175]; 256 threads
__global__ __launch_bounds__(256) void d2_red_trace_k(
    const float* __restrict__ part, const float* __restrict__ outb, float* __restrict__ dout,
    const unsigned short* __restrict__ trh, const unsigned short* __restrict__ trl,
    const unsigned short* __restrict__ w1bf,
    const float* __restrict__ b1, const float* __restrict__ w2t, const float* __restrict__ b2,
    float* __restrict__ act, unsigned short* __restrict__ aTh, unsigned short* __restrict__ aTl,
    int t, int nsO){
    __shared__ __align__(16) char U[45824];
    int tid = threadIdx.x;
    int bid = blockIdx.x;
    if (bid < 128){
        if (t <= 0) return;
        reduce_row(part, outb, dout, (float*)U, bid, t - 1, tid, nsO);
    } else {
        // ---- trace_proc(t): per-d block ----
        int d = bid - 128;
        unsigned short* Ah   = (unsigned short*)U;             // 128*40*2 = 10240 B
        unsigned short* Al   = (unsigned short*)(U + 10240);   // 10240 B
        unsigned short* Bbuf = (unsigned short*)(U + 20480);   // 4096*2 = 8192 B
        float* hh  = (float*)(U + 28672);                      // 128*33*4 = 16896 B
        float* w2s = (float*)(U + 45568);                      // 256 B

        for (int i = tid; i < MEMN*64; i += 256){
            int m = i >> 6, bp = i & 63;
            int phys = t + 1 + m; if (phys >= MEMN) phys -= MEMN; if (phys >= MEMN) phys -= MEMN;
            long gaddr = ((long)phys*DMODEL + d)*BB + bp*2;
            ushort2 vh = *(const ushort2*)(trh + gaddr);
            ushort2 vl = *(const ushort2*)(trl + gaddr);
            Ah[(bp*2+0)*40 + m] = vh.x; Ah[(bp*2+1)*40 + m] = vh.y;
            Al[(bp*2+0)*40 + m] = vl.x; Al[(bp*2+1)*40 + m] = vl.y;
        }
        for (int i = tid; i < 7*128; i += 256){
            int m = MEMN + (i >> 7), b = i & 127;
            Ah[b*40 + m] = 0; Al[b*40 + m] = 0;
        }
        {
            const uint4* src = (const uint4*)(w1bf + (long)d*4096);
            uint4* dst = (uint4*)Bbuf;
            for (int i = tid; i < 512; i += 256) dst[i] = src[i];
        }
        if (tid < 64) w2s[tid] = w2t[(long)d*64 + tid];
        __syncthreads();

        int wid = tid >> 6, lane = tid & 63;
        int mrow = lane & 15, kq = lane >> 4;
        bf16x8 ahf[2], alf[2], bhf[4], blf[4];
#pragma unroll
        for (int bt = 0; bt < 2; ++bt){
            int r = (wid*2 + bt)*16 + mrow;
            ahf[bt] = *(const bf16x8*)&Ah[r*40 + kq*8];
            alf[bt] = *(const bf16x8*)&Al[r*40 + kq*8];
        }
#pragma unroll
        for (int ht = 0; ht < 4; ++ht){
            int r = ht*16 + mrow;
            bhf[ht] = *(const bf16x8*)&Bbuf[r*32 + kq*8];
            blf[ht] = *(const bf16x8*)&Bbuf[2048 + r*32 + kq*8];
        }
        f32x4 c[2][4];
#pragma unroll
        for (int bt = 0; bt < 2; ++bt)
#pragma unroll
            for (int ht = 0; ht < 4; ++ht){
                c[bt][ht] = (f32x4){0.f,0.f,0.f,0.f};
                c[bt][ht] = __builtin_amdgcn_mfma_f32_16x16x32_bf16(ahf[bt], bhf[ht], c[bt][ht], 0, 0, 0);
                c[bt][ht] = __builtin_amdgcn_mfma_f32_16x16x32_bf16(alf[bt], bhf[ht], c[bt][ht], 0, 0, 0);
                c[bt][ht] = __builtin_amdgcn_mfma_f32_16x16x32_bf16(ahf[bt], blf[ht], c[bt][ht], 0, 0, 0);
            }
        int quad = lane >> 4;
#pragma unroll
        for (int bt = 0; bt < 2; ++bt){
            int bb0 = (wid*2 + bt)*16 + quad*4;
#pragma unroll
            for (int ht = 0; ht < 2; ++ht){
                int h = ht*16 + (lane & 15);
                float ba = b1[(long)d*64 + h];
                float bg = b1[(long)d*64 + 32 + h];
#pragma unroll
                for (int reg = 0; reg < 4; ++reg){
                    float a = c[bt][ht][reg] + ba;
                    float g = c[bt][ht+2][reg] + bg;
                    hh[(bb0+reg)*33 + h] = a * sigm(g);
                }
            }
        }
        __syncthreads();
        if (tid < 128){
            int bb = tid;
            float o0 = b2[(long)d*2+0], o1 = b2[(long)d*2+1];
#pragma unroll
            for (int h = 0; h < 32; ++h){
                float hv = hh[bb*33 + h];
                o0 += hv * w2s[h*2+0];
                o1 += hv * w2s[h*2+1];
            }
            float a = o0 * sigm(o1);
            act[(long)d*BB + bb] = a;
            unsigned short h16 = f2bf(a);
            aTh[(long)bb*DMODEL + d] = h16;
            aTl[(long)bb*DMODEL + d] = f2bf(a - bf2f(h16));
        }
    }
}

// D3(t): syn(t+1) [blocks 0..64*nsS) ∥ pairwise(t) [next 528 blocks]; 256 threads
// syn: single-panel staging (R7-proven), runtime split count nsS, K/split = DMODEL/nsS
__global__ __launch_bounds__(256) void d3_syn_pair_k(
    const unsigned short* __restrict__ Ah, const unsigned short* __restrict__ Al,
    const unsigned short* __restrict__ Bh, const unsigned short* __restrict__ Bl,
    float* __restrict__ zpart,
    const float* __restrict__ act, const float* __restrict__ decay,
    const int* __restrict__ il, const int* __restrict__ ir,
    const int* __restrict__ rowOf, const int* __restrict__ rowstart,
    float* __restrict__ alpha, unsigned short* __restrict__ syncb, int t, int nsS){
    __shared__ __align__(16) char U[24576];
    int tid = threadIdx.x;
    int bid = blockIdx.x;
    if (bid < 64*nsS){
        // ---- syn(t+1): zpart[s][128][4096-slice] = actT @ swT^T (hi/lo bf16) ----
        if (t >= ITERS-1) return;
        unsigned short* As_h = (unsigned short*)U;             // 8192 B
        unsigned short* As_l = (unsigned short*)(U + 8192);    // 8192 B
        unsigned short* Bs_h = (unsigned short*)(U + 16384);   // 4096 B
        unsigned short* Bs_l = (unsigned short*)(U + 20480);   // 4096 B
        int wid = tid >> 6, lane = tid & 63;
        int wm = (wid & 1)*64, wn = (wid >> 1)*32;
        int mrow = lane & 15, kq = lane >> 4;
        int srow = tid >> 2;
        int ksg  = (tid & 3)*8;
        int nb = bid & 63;
        int s  = bid >> 6;
        int kspl = DMODEL/nsS;          // 256 or 128
        int rounds = kspl >> 5;         // 8 or 4

        f32x4 c[4][2];
#pragma unroll
        for (int a = 0; a < 4; ++a)
#pragma unroll
            for (int b = 0; b < 2; ++b) c[a][b] = (f32x4){0.f,0.f,0.f,0.f};

        long koff0 = (long)s*kspl + ksg;
        const unsigned short* gAh1 = Ah + (long)srow*DMODEL      + koff0;
        const unsigned short* gAh2 = Ah + (long)(srow+64)*DMODEL + koff0;
        const unsigned short* gAl1 = Al + (long)srow*DMODEL      + koff0;
        const unsigned short* gAl2 = Al + (long)(srow+64)*DMODEL + koff0;
        const unsigned short* gBh  = Bh + (long)(nb*64+srow)*DMODEL + koff0;
        const unsigned short* gBl  = Bl + (long)(nb*64+srow)*DMODEL + koff0;
        unsigned short* lAh1 = As_h + wid*512;
        unsigned short* lAh2 = As_h + 2048 + wid*512;
        unsigned short* lAl1 = As_l + wid*512;
        unsigned short* lAl2 = As_l + 2048 + wid*512;
        unsigned short* lBh  = Bs_h + wid*512;
        unsigned short* lBl  = Bs_l + wid*512;

        for (int ks = 0; ks < rounds; ++ks){
            int o = ks*32;
            gload16(gAh1 + o, lAh1);
            gload16(gAh2 + o, lAh2);
            gload16(gAl1 + o, lAl1);
            gload16(gAl2 + o, lAl2);
            gload16(gBh  + o, lBh);
            gload16(gBl  + o, lBl);
            __syncthreads();
            bf16x8 ah[4], al[4], bh[2], bl[2];
#pragma unroll
            for (int x = 0; x < 4; ++x){
                ah[x] = *(const bf16x8*)&As_h[(wm + x*16 + mrow)*32 + kq*8];
                al[x] = *(const bf16x8*)&As_l[(wm + x*16 + mrow)*32 + kq*8];
            }
#pragma unroll
            for (int y = 0; y < 2; ++y){
                bh[y] = *(const bf16x8*)&Bs_h[(wn + y*16 + mrow)*32 + kq*8];
                bl[y] = *(const bf16x8*)&Bs_l[(wn + y*16 + mrow)*32 + kq*8];
            }
#pragma unroll
            for (int a = 0; a < 4; ++a)
#pragma unroll
                for (int b = 0; b < 2; ++b){
                    c[a][b] = __builtin_amdgcn_mfma_f32_16x16x32_bf16(ah[a], bh[b], c[a][b], 0, 0, 0);
                    c[a][b] = __builtin_amdgcn_mfma_f32_16x16x32_bf16(al[a], bh[b], c[a][b], 0, 0, 0);
                    c[a][b] = __builtin_amdgcn_mfma_f32_16x16x32_bf16(ah[a], bl[b], c[a][b], 0, 0, 0);
                }
            __syncthreads();
        }
        float* outp = zpart + (long)s*(BB*4096);
#pragma unroll
        for (int a = 0; a < 4; ++a)
#pragma unroll
            for (int b = 0; b < 2; ++b){
                int r0 = wm + a*16 + (lane >> 4)*4;
                int col = nb*64 + wn + b*16 + (lane & 15);
#pragma unroll
                for (int reg = 0; reg < 4; ++reg)
                    outp[(long)(r0+reg)*4096 + col] = c[a][b][reg];
            }
    } else {
        // ---- pairwise(t) + alpha update + sync write ----
        if (t < 0) return;
        int idx = bid - 64*nsS;      // [0, 528)
        int xx = idx % 132;
        int bg = idx / 132;
        int k = xx*256 + tid;
        int blo = bg*32, bhi = blo + 32;
        if (k >= SYNCN){
            if (k < KPAD)
                for (int b = blo; b < bhi; ++b) syncb[(long)b*KPAD + k] = 0;
            return;
        }
        int i = rowOf[k];
        int j = i + (k - rowstart[i]);
        float cc = fminf(fmaxf(decay[k], 0.f), 15.f);
        float r = __expf(-cc);
        float bet;
        if (cc < 1e-30f) bet = (float)(t + 2);
        else {
            float e1 = expm1f(-cc);
            float et = expm1f(-cc*(float)(t+1));
            bet = 1.f + et + et/e1;
        }
        float rs = rsqrtf(bet);
        const float* aL = act + (long)il[i]*BB;
        const float* aR = act + (long)ir[j]*BB;
        for (int b = blo; b < bhi; ++b){
            float pp = aL[b]*aR[b];
            float al = r*alpha[(long)b*SYNCN + k] + pp;
            alpha[(long)b*SYNCN + k] = al;
            syncb[(long)b*KPAD + k] = f2bf(al*rs);
        }
    }
}

// standalone out_gemm for the final iteration's projection (runtime splits)
__global__ __launch_bounds__(256) void out_gemm_k(const unsigned short* __restrict__ Abf,
    const unsigned short* __restrict__ Bbf, float* __restrict__ part, int KCHo){
    int n_base = blockIdx.x*64;
    int sk = blockIdx.y;
    int tid = threadIdx.x;
    int wid = tid >> 6, lane = tid & 63;
    int wm = (wid & 1)*64, wn = (wid >> 1)*32;
    long k_base = (long)sk*KCHo;
    __shared__ __align__(16) unsigned short As[128*32];
    __shared__ __align__(16) unsigned short Bs[64*32];
    f32x4 c[4][2];
#pragma unroll
    for (int a = 0; a < 4; ++a)
#pragma unroll
        for (int b = 0; b < 2; ++b) c[a][b] = (f32x4){0.f,0.f,0.f,0.f};

    int mrow = lane & 15, kq = lane >> 4;
    int srow = tid >> 2;
    int ksg  = (tid & 3)*8;
    const unsigned short* gA1 = Abf + (long)srow*KPAD      + k_base + ksg;
    const unsigned short* gA2 = Abf + (long)(srow+64)*KPAD + k_base + ksg;
    const unsigned short* gB  = Bbf + (long)(n_base+srow)*KPAD + k_base + ksg;
    unsigned short* lA1 = As + wid*512;
    unsigned short* lA2 = As + 2048 + wid*512;
    unsigned short* lB  = Bs + wid*512;

    int NS = KCHo >> 5;
    for (int ks = 0; ks < NS; ++ks){
        int o = ks*32;
        gload16(gA1 + o, lA1);
        gload16(gA2 + o, lA2);
        gload16(gB  + o, lB);
        __syncthreads();
        bf16x8 af[4], bf[2];
#pragma unroll
        for (int x = 0; x < 4; ++x)
            af[x] = *(const bf16x8*)&As[(wm + x*16 + mrow)*32 + kq*8];
#pragma unroll
        for (int y = 0; y < 2; ++y)
            bf[y] = *(const bf16x8*)&Bs[(wn + y*16 + mrow)*32 + kq*8];
#pragma unroll
        for (int a = 0; a < 4; ++a)
#pragma unroll
            for (int b = 0; b < 2; ++b)
                c[a][b] = __builtin_amdgcn_mfma_f32_16x16x32_bf16(af[a], bf[b], c[a][b], 0, 0, 0);
        __syncthreads();
    }
    float* outp = part + (long)sk*(128*NPAD);
#pragma unroll
    for (int a = 0; a < 4; ++a)
#pragma unroll
        for (int b = 0; b < 2; ++b){
            int r0 = wm + a*16 + (lane >> 4)*4;
            int col = n_base + wn + b*16 + (lane & 15);
#pragma unroll
            for (int reg = 0; reg < 4; ++reg)
                outp[(long)(r0+reg)*NPAD + col] = c[a][b][reg];
        }
}

// standalone reduce for the last iteration (t = ITERS-1)
__global__ __launch_bounds__(256) void reduce_final_k(const float* __restrict__ part,
    const float* __restrict__ outb, float* __restrict__ dout, int nsO){
    __shared__ float red[8];
    reduce_row(part, outb, dout, red, blockIdx.x, ITERS-1, threadIdx.x, nsO);
}

// ---------------- host ----------------

extern "C" void kernel_launch(void* const* d_in, const int* in_sizes, int n_in,
                              void* d_out, int out_size, void* d_ws, size_t ws_size,
                              hipStream_t stream){
    const float* x      = (const float*)d_in[0];
    const float* syn_w  = (const float*)d_in[1];
    const float* syn_b  = (const float*)d_in[2];
    const float* ln_g   = (const float*)d_in[3];
    const float* ln_b   = (const float*)d_in[4];
    const float* tp_w1  = (const float*)d_in[5];
    const float* tp_b1  = (const float*)d_in[6];
    const float* tp_w2  = (const float*)d_in[7];
    const float* tp_b2  = (const float*)d_in[8];
    const float* sas    = (const float*)d_in[9];
    const float* strc   = (const float*)d_in[10];
    const float* decay  = (const float*)d_in[11];
    const float* out_w  = (const float*)d_in[12];
    const float* out_b  = (const float*)d_in[13];
    const int*   il     = (const int*)d_in[14];
    const int*   ir     = (const int*)d_in[15];
    float* dout = (float*)d_out;

    char* ws = (char*)d_ws;
    size_t off = 0;
    auto algn = [](size_t b){ return (b + 255) & ~(size_t)255; };
    auto alloc = [&](size_t bytes)->void*{
        void* p = ws + off;
        off += algn(bytes);
        return p;
    };
    // ---- fixed allocations (identical both modes) ----
    unsigned short* trh = (unsigned short*)alloc((size_t)MEMN*DMODEL*BB*2);  // 13.1 MB [m][d][b]
    unsigned short* trl = (unsigned short*)alloc((size_t)MEMN*DMODEL*BB*2);  // 13.1 MB
    float* act     = (float*)alloc((size_t)DMODEL*BB*4);          // 1 MB     [d][b]
    float* C0      = (float*)alloc((size_t)BB*4096*4);            // 2.1 MB
    float* xt      = (float*)alloc((size_t)DIN*BB*4);             // 0.26 MB  [k][b]
    float* w2t     = (float*)alloc((size_t)DMODEL*64*4);          // 0.52 MB  [d][h*2+o]
    unsigned short* w1bf = (unsigned short*)alloc((size_t)DMODEL*4096*2);    // 16.8 MB [d][plane][h*32+m]
    float* alpha   = (float*)alloc((size_t)BB*SYNCN*4);           // 16.8 MB
    unsigned short* syncb = (unsigned short*)alloc((size_t)BB*KPAD*2);   // 8.65 MB [b][k]
    unsigned short* wbt   = (unsigned short*)alloc((size_t)NPAD*KPAD*2); // 69.2 MB [n][k]
    unsigned short* swT_h = (unsigned short*)alloc((size_t)4096*DMODEL*2); // 16.8 MB [n][k]
    unsigned short* swT_l = (unsigned short*)alloc((size_t)4096*DMODEL*2); // 16.8 MB
    unsigned short* aT_h  = (unsigned short*)alloc((size_t)BB*DMODEL*2);   // 0.52 MB [b][d]
    unsigned short* aT_l  = (unsigned short*)alloc((size_t)BB*DMODEL*2);   // 0.52 MB
    int* rowOf    = (int*)alloc((size_t)SYNCN*4);
    int* rowstart = (int*)alloc((size_t)NSY*4);
    size_t fixedEnd = off;

    // ---- workspace-gated split counts (variable buffers allocated last) ----
    int nsO = 66, nsS = 16;   // preferred: out 66 splits (16 rounds), syn 16 splits (4 rounds)
    {
        auto tot = [&](int no, int ns){
            return fixedEnd + algn((size_t)no*BB*NPAD*4) + algn((size_t)ns*BB*4096*4);
        };
        if (tot(66,16) > ws_size){
            if      (tot(66, 8) <= ws_size){ nsO = 66; nsS = 8;  }
            else if (tot(32,16) <= ws_size){ nsO = 32; nsS = 16; }
            else                            { nsO = 32; nsS = 8;  }   // R7-equivalent
        }
    }
    const int KCHo = KPAD / nsO;    // 512 or 1056
    float* part  = (float*)alloc((size_t)nsO*BB*NPAD*4);   // out split-K partials
    float* w1t   = part;                                   // init-only alias (13.1 MB <= part)
    float* zpart = (float*)alloc((size_t)nsS*BB*4096*4);   // syn split-K partials
    (void)ws_size; (void)in_sizes; (void)n_in; (void)out_size;

    // ---- once-per-launch precompute ----
    init_trace_k<<<8192, 256, 0, stream>>>(strc, trh, trl);
    init_act_k<<<1024, 256, 0, stream>>>(sas, act);
    init_alpha_k<<<256, 256, 0, stream>>>(sas, il, ir, alpha);
    init_rowmap_k<<<256, 256, 0, stream>>>(rowOf, rowstart);
    transpose_f32_k<<<dim3(32, 25), 256, 0, stream>>>(tp_w1, w1t, 1600, 2048);
    w1bf_prep_k<<<2048, 256, 0, stream>>>(w1t, w1bf);
    transpose_f32_k<<<dim3(32, 1),  256, 0, stream>>>(tp_w2, w2t, 64, 2048);
    transpose_f32_k<<<dim3(8, 2),   256, 0, stream>>>(x, xt, 128, 512);
    wbf_transpose_k<<<dim3(KPAD/64, 16), 256, 0, stream>>>(out_w, wbt);
    swt_convert_k<<<dim3(32, 64), 256, 0, stream>>>(syn_w, swT_h, swT_l);
    gemm_syn_k<<<64, 256, 0, stream>>>(xt, syn_w, syn_b, C0);
    act_convert_k<<<dim3(32, 2), 256, 0, stream>>>(act, aT_h, aT_l);

    // ---- prologue: syn(0) (D3 with t=-1: pairwise skipped) ----
    d3_syn_pair_k<<<64*nsS + 528, 256, 0, stream>>>(aT_h, aT_l, swT_h, swT_l, zpart,
                                                    act, decay, il, ir, rowOf, rowstart,
                                                    alpha, syncb, -1, nsS);

    // ---- 24 iterations, 3 dispatches each ----
    for (int t = 0; t < ITERS; ++t){
        d1_out_glu_k<<<16*nsO + 128, 256, 0, stream>>>(syncb, wbt, part,
                                                       C0, zpart, ln_g, ln_b, trh, trl,
                                                       t % MEMN, t > 0, nsO, KCHo, nsS);
        d2_red_trace_k<<<2176, 256, 0, stream>>>(part, out_b, dout,
                                                 trh, trl, w1bf, tp_b1, w2t, tp_b2,
                                                 act, aT_h, aT_l, t, nsO);
        d3_syn_pair_k<<<64*nsS + 528, 256, 0, stream>>>(aT_h, aT_l, swT_h, swT_l, zpart,
                                                        act, decay, il, ir, rowOf, rowstart,
                                                        alpha, syncb, t, nsS);
    }
    // ---- tail: out(23) + reduce(23) ----
    out_gemm_k<<<dim3(16, nsO), 256, 0, stream>>>(syncb, wbt, part, KCHo);
    reduce_final_k<<<128, 256, 0, stream>>>(part, out_b, dout, nsO);
}

// Round 11
// 2415.536 us; speedup vs baseline: 1.5763x; 1.5763x over previous
//
#include <hip/hip_runtime.h>
#include <stdint.h>

#define BB      128
#define DIN     512
#define DMODEL  2048
#define MEMN    25
#define NSY     256
#define OUTD    1000
#define ITERS   24
#define SYNCN   32896
#define KPAD    33792      // 32 splits * 1056 (33 k-steps of 32)
#define NPAD    1024
#define NSPLIT  32
#define KCH     1056
#define PREDTOT (BB*OUTD*ITERS)

typedef __attribute__((ext_vector_type(8))) short bf16x8;
typedef __attribute__((ext_vector_type(4))) float f32x4;

__device__ __forceinline__ unsigned short f2bf(float x){
    unsigned int u = __float_as_uint(x);
    u += 0x7fffu + ((u >> 16) & 1u);
    return (unsigned short)(u >> 16);
}
__device__ __forceinline__ float bf2f(unsigned short h){
    unsigned int u = ((unsigned int)h) << 16;
    return __uint_as_float(u);
}
__device__ __forceinline__ float sigm(float x){ return 1.f/(1.f + __expf(-x)); }

// async global->LDS, 16B per lane; LDS dest is wave-uniform base + lane*16
__device__ __forceinline__ void gload16(const unsigned short* g, unsigned short* l){
    __builtin_amdgcn_global_load_lds(
        (const __attribute__((address_space(1))) unsigned int*)(const void*)g,
        (__attribute__((address_space(3))) unsigned int*)(void*)l,
        16, 0, 0);
}

// 256-thread reduce+softmax+entropy for one batch row b at iteration t.
// red = 8-float shared scratch. Writes dout directly (final layout).
// NOTE: NSPLIT is compile-time -- the split-sum loop MUST fully unroll so the
// 32 loads pipeline; a runtime trip count serializes into a ~75us latency chain (R10).
__device__ __forceinline__ void reduce_row(const float* __restrict__ part, const float* __restrict__ outb,
    float* __restrict__ dout, float* red, int b, int t, int tid){
    float v[4];
    float m = -1e30f;
#pragma unroll
    for (int q = 0; q < 4; ++q){
        int n = q*256 + tid;
        float s;
        if (n < OUTD){
            s = outb[n];
            for (int sk = 0; sk < NSPLIT; ++sk)
                s += part[(long)sk*(BB*NPAD) + (long)b*NPAD + n];
        } else s = -1e30f;
        v[q] = s;
        m = fmaxf(m, s);
    }
#pragma unroll
    for (int off = 32; off; off >>= 1) m = fmaxf(m, __shfl_down(m, off));
    int w = tid >> 6;
    if ((tid & 63) == 0) red[w] = m;
    __syncthreads();
    float M = fmaxf(fmaxf(red[0], red[1]), fmaxf(red[2], red[3]));
    __syncthreads();
    float z = 0.f, s2 = 0.f;
#pragma unroll
    for (int q = 0; q < 4; ++q){
        int n = q*256 + tid;
        if (n < OUTD){
            float e = __expf(v[q] - M);
            z += e; s2 += e*v[q];
        }
    }
#pragma unroll
    for (int off = 32; off; off >>= 1){
        z  += __shfl_down(z, off);
        s2 += __shfl_down(s2, off);
    }
    if ((tid & 63) == 0){ red[w] = z; red[4+w] = s2; }
    __syncthreads();
    if (tid == 0){
        float Z = red[0]+red[1]+red[2]+red[3];
        float S = red[4]+red[5]+red[6]+red[7];
        float logZ = M + __logf(Z);
        float ne = (logZ - S/Z) / 6.907755278982137f;
        dout[PREDTOT + b*48 + t] = ne;
        dout[PREDTOT + b*48 + 24 + t] = 1.f - ne;
    }
#pragma unroll
    for (int q = 0; q < 4; ++q){
        int n = q*256 + tid;
        if (n < OUTD) dout[(long)b*(OUTD*ITERS) + (long)n*ITERS + t] = v[q];
    }
}

// ---------------- init kernels (run every launch: ws is re-poisoned) ----------------

__global__ __launch_bounds__(256) void init_trace_k(const float* __restrict__ st,
    unsigned short* __restrict__ trh, unsigned short* __restrict__ trl){
    const long N = (long)MEMN*DMODEL*BB;
    for (long i = (long)blockIdx.x*256 + threadIdx.x; i < N; i += (long)gridDim.x*256){
        int m = (int)(i / (DMODEL*BB));
        int rem = (int)(i % (DMODEL*BB));
        int d = rem >> 7;
        float v = st[d*MEMN + m];
        unsigned short h = f2bf(v);
        trh[i] = h;
        trl[i] = f2bf(v - bf2f(h));
    }
}

__global__ __launch_bounds__(256) void init_act_k(const float* __restrict__ sas, float* __restrict__ act){
    for (int i = blockIdx.x*256 + threadIdx.x; i < DMODEL*BB; i += gridDim.x*256)
        act[i] = sas[i >> 7];
}

__global__ __launch_bounds__(256) void init_alpha_k(const float* __restrict__ sas,
    const int* __restrict__ il, const int* __restrict__ ir, float* __restrict__ alpha){
    int i = blockIdx.x, tid = threadIdx.x;
    if (tid >= NSY - i) return;
    int j = i + tid;
    int k = i*(2*NSY - i + 1)/2 + tid;
    float a0 = sas[il[i]] * sas[ir[j]];
    for (int b = 0; b < BB; ++b) alpha[b*SYNCN + k] = a0;
}

__global__ __launch_bounds__(256) void init_rowmap_k(int* __restrict__ rowOf, int* __restrict__ rowstart){
    int i = blockIdx.x, tid = threadIdx.x;
    int start = i*(2*NSY - i + 1)/2;
    int len = NSY - i;
    if (tid == 0) rowstart[i] = start;
    for (int t = tid; t < len; t += 256) rowOf[start + t] = i;
}

__global__ __launch_bounds__(256) void transpose_f32_k(const float* __restrict__ in, float* __restrict__ out, int R, int C){
    __shared__ float S[64][65];
    int r0 = blockIdx.y*64, c0 = blockIdx.x*64;
    for (int i = threadIdx.x; i < 64*64; i += 256){
        int rr = i >> 6, cc = i & 63;
        int r = r0+rr, c = c0+cc;
        if (r < R && c < C) S[rr][cc] = in[(long)r*C + c];
    }
    __syncthreads();
    for (int i = threadIdx.x; i < 64*64; i += 256){
        int cc = i >> 6, rr = i & 63;
        int r = r0+rr, c = c0+cc;
        if (r < R && c < C) out[(long)c*R + r] = S[rr][cc];
    }
}

// w1t [d][m*64+h] f32 -> w1bf [d][plane(hi=0,lo=1)][h*32+m] bf16, m padded 25->32 with zeros
__global__ __launch_bounds__(256) void w1bf_prep_k(const float* __restrict__ w1t, unsigned short* __restrict__ w1bf){
    int d = blockIdx.x, tid = threadIdx.x;
    __shared__ float S[1600];
    for (int i = tid; i < 1600; i += 256) S[i] = w1t[(long)d*1600 + i];
    __syncthreads();
    for (int i = tid; i < 2048; i += 256){
        int h = i >> 5, m = i & 31;
        float v = (m < MEMN) ? S[m*64 + h] : 0.f;
        unsigned short hi = f2bf(v);
        unsigned short lo = f2bf(v - bf2f(hi));
        w1bf[(long)d*4096 + i]        = hi;
        w1bf[(long)d*4096 + 2048 + i] = lo;
    }
}

// out_w f32 [SYNCN][OUTD] -> bf16 [NPAD][KPAD] (transposed); 64x64 tiles
__global__ __launch_bounds__(256) void wbf_transpose_k(const float* __restrict__ w, unsigned short* __restrict__ wt){
    __shared__ float S[64][65];
    int k0 = blockIdx.x*64, n0 = blockIdx.y*64;
    int tid = threadIdx.x;
    if (k0 >= SYNCN){
        uint4 z = {0u,0u,0u,0u};
#pragma unroll
        for (int p = 0; p < 2; ++p){
            int i = tid + p*256;
            int nn = i >> 3, k8 = (i & 7)*8;
            *(uint4*)(wt + (long)(n0+nn)*KPAD + k0 + k8) = z;
        }
        return;
    }
    const long MAXI = (long)SYNCN*OUTD - 4;
#pragma unroll
    for (int p = 0; p < 4; ++p){
        int i = tid + p*256;
        int rr = i >> 4, c4 = (i & 15)*4;
        long idx = (long)(k0+rr)*OUTD + n0 + c4;
        if (idx > MAXI) idx = MAXI;
        float4 v = *(const float4*)(w + idx);
        S[rr][c4+0]=v.x; S[rr][c4+1]=v.y; S[rr][c4+2]=v.z; S[rr][c4+3]=v.w;
    }
    __syncthreads();
#pragma unroll
    for (int p = 0; p < 4; ++p){
        int i = tid + p*256;
        int nn = i >> 4, k4 = (i & 15)*4;
        ushort4 o;
        o.x = f2bf(S[k4+0][nn]); o.y = f2bf(S[k4+1][nn]);
        o.z = f2bf(S[k4+2][nn]); o.w = f2bf(S[k4+3][nn]);
        *(ushort4*)(wt + (long)(n0+nn)*KPAD + k0 + k4) = o;
    }
}

// syn_w rows [512..2560) f32 [k][4096] -> swT hi/lo bf16 [n=4096][k=2048]; 64x64 tiles
__global__ __launch_bounds__(256) void swt_convert_k(const float* __restrict__ w,
    unsigned short* __restrict__ th, unsigned short* __restrict__ tl){
    __shared__ float S[64][65];
    int k0 = blockIdx.x*64, n0 = blockIdx.y*64;
    int tid = threadIdx.x;
#pragma unroll
    for (int p = 0; p < 4; ++p){
        int i = tid + p*256;
        int rr = i >> 4, c4 = (i & 15)*4;
        float4 v = *(const float4*)(w + (long)(512 + k0 + rr)*4096 + n0 + c4);
        S[rr][c4+0]=v.x; S[rr][c4+1]=v.y; S[rr][c4+2]=v.z; S[rr][c4+3]=v.w;
    }
    __syncthreads();
#pragma unroll
    for (int p = 0; p < 4; ++p){
        int i = tid + p*256;
        int nn = i >> 4, k4 = (i & 15)*4;
        ushort4 oh, ol;
        float v0 = S[k4+0][nn], v1 = S[k4+1][nn], v2 = S[k4+2][nn], v3 = S[k4+3][nn];
        oh.x = f2bf(v0); oh.y = f2bf(v1); oh.z = f2bf(v2); oh.w = f2bf(v3);
        ol.x = f2bf(v0 - bf2f(oh.x)); ol.y = f2bf(v1 - bf2f(oh.y));
        ol.z = f2bf(v2 - bf2f(oh.z)); ol.w = f2bf(v3 - bf2f(oh.w));
        *(ushort4*)(th + (long)(n0+nn)*DMODEL + k0 + k4) = oh;
        *(ushort4*)(tl + (long)(n0+nn)*DMODEL + k0 + k4) = ol;
    }
}

// act [d=2048][b=128] f32 -> aT hi/lo bf16 [b][d]  (init only)
__global__ __launch_bounds__(256) void act_convert_k(const float* __restrict__ act,
    unsigned short* __restrict__ th, unsigned short* __restrict__ tl){
    __shared__ float S[64][65];
    int d0 = blockIdx.x*64, b0 = blockIdx.y*64;
    int tid = threadIdx.x;
#pragma unroll
    for (int p = 0; p < 4; ++p){
        int i = tid + p*256;
        int rr = i >> 4, c4 = (i & 15)*4;
        float4 v = *(const float4*)(act + (long)(d0+rr)*BB + b0 + c4);
        S[rr][c4+0]=v.x; S[rr][c4+1]=v.y; S[rr][c4+2]=v.z; S[rr][c4+3]=v.w;
    }
    __syncthreads();
#pragma unroll
    for (int p = 0; p < 4; ++p){
        int i = tid + p*256;
        int nn = i >> 4, k4 = (i & 15)*4;
        unsigned short h[4], l[4];
#pragma unroll
        for (int q = 0; q < 4; ++q){
            float v = S[k4+q][nn];
            h[q] = f2bf(v);
            l[q] = f2bf(v - bf2f(h[q]));
        }
        *(ushort4*)(th + (long)(b0+nn)*DMODEL + d0 + k4) = ushort4{h[0],h[1],h[2],h[3]};
        *(ushort4*)(tl + (long)(b0+nn)*DMODEL + d0 + k4) = ushort4{l[0],l[1],l[2],l[3]};
    }
}

// fp32 GEMM (once, for C0): out[b][j](4096) = bias + sum_k A[k][b]*Bw[k][j], K=512
__global__ __launch_bounds__(256) void gemm_syn_k(const float* __restrict__ A, const float* __restrict__ Bw,
    const float* __restrict__ bias, float* __restrict__ out){
    int j_base = blockIdx.x*64;
    int tid = threadIdx.x;
    __shared__ float As[16][128];
    __shared__ float Bs[16][68];
    int bg = tid & 15, jg = tid >> 4;
    int b0 = bg*8, j0 = jg*4;
    float acc[8][4];
#pragma unroll
    for (int i = 0; i < 8; ++i)
#pragma unroll
        for (int q = 0; q < 4; ++q) acc[i][q] = 0.f;
    for (int kt = 0; kt < 32; ++kt){
        {
            int i0 = tid*8;
            int kk = i0 >> 7, bb = i0 & 127;
            const float4* src = (const float4*)(A + (long)(kt*16+kk)*BB + bb);
            float4 v0 = src[0], v1 = src[1];
            *(float4*)&As[kk][bb]   = v0;
            *(float4*)&As[kk][bb+4] = v1;
        }
        {
            int i0 = tid*4;
            int kk = i0 >> 6, jj = i0 & 63;
            float4 v = *(const float4*)(Bw + (long)(kt*16+kk)*4096 + j_base + jj);
            *(float4*)&Bs[kk][jj] = v;
        }
        __syncthreads();
#pragma unroll
        for (int kk = 0; kk < 16; ++kk){
            float a[8], bv[4];
            *(float4*)&a[0] = *(float4*)&As[kk][b0];
            *(float4*)&a[4] = *(float4*)&As[kk][b0+4];
            *(float4*)&bv[0] = *(float4*)&Bs[kk][j0];
#pragma unroll
            for (int i = 0; i < 8; ++i)
#pragma unroll
                for (int q = 0; q < 4; ++q) acc[i][q] += a[i]*bv[q];
        }
        __syncthreads();
    }
#pragma unroll
    for (int i = 0; i < 8; ++i){
        int bb = b0 + i;
        float4 v;
        v.x = acc[i][0]+bias[j_base+j0+0]; v.y = acc[i][1]+bias[j_base+j0+1];
        v.z = acc[i][2]+bias[j_base+j0+2]; v.w = acc[i][3]+bias[j_base+j0+3];
        *(float4*)(out + (long)bb*4096 + j_base + j0) = v;
    }
}

// ---------------- per-iteration fused dispatches ----------------
// D1(t): out(t-1) [blocks 0..511] ∥ glu(t) [next 128 blocks]; 256 threads
__global__ __launch_bounds__(256) void d1_out_glu_k(
    const unsigned short* __restrict__ Abf, const unsigned short* __restrict__ Bbf,
    float* __restrict__ part,
    const float* __restrict__ C0, const float* __restrict__ zp,
    const float* __restrict__ lng, const float* __restrict__ lnb,
    unsigned short* __restrict__ trh, unsigned short* __restrict__ trl,
    int slot, int do_out){
    __shared__ __align__(16) char U[24576];
    int tid = threadIdx.x;
    int bid = blockIdx.x;
    if (bid < 512){
        // ---- out_gemm(t-1): part[sk][128][NPAD] = sync @ wt^T ----
        if (!do_out) return;
        unsigned short* As = (unsigned short*)U;           // 128*32 = 8192 B
        unsigned short* Bs = (unsigned short*)(U + 8192);  // 64*32  = 4096 B
        int wid = tid >> 6, lane = tid & 63;
        int wm = (wid & 1)*64, wn = (wid >> 1)*32;
        int mrow = lane & 15, kq = lane >> 4;
        int srow = tid >> 2;
        int ksg  = (tid & 3)*8;
        int sk = bid >> 4;
        int n_base = (bid & 15)*64;
        long k_base = (long)sk*KCH;

        f32x4 c[4][2];
#pragma unroll
        for (int a = 0; a < 4; ++a)
#pragma unroll
            for (int b = 0; b < 2; ++b) c[a][b] = (f32x4){0.f,0.f,0.f,0.f};

        const unsigned short* gA1 = Abf + (long)srow*KPAD      + k_base + ksg;
        const unsigned short* gA2 = Abf + (long)(srow+64)*KPAD + k_base + ksg;
        const unsigned short* gB  = Bbf + (long)(n_base+srow)*KPAD + k_base + ksg;
        unsigned short* lA1 = As + wid*512;
        unsigned short* lA2 = As + 2048 + wid*512;
        unsigned short* lB  = Bs + wid*512;

        for (int ks = 0; ks < KCH/32; ++ks){
            int o = ks*32;
            gload16(gA1 + o, lA1);
            gload16(gA2 + o, lA2);
            gload16(gB  + o, lB);
            __syncthreads();
            bf16x8 af[4], bf[2];
#pragma unroll
            for (int x = 0; x < 4; ++x)
                af[x] = *(const bf16x8*)&As[(wm + x*16 + mrow)*32 + kq*8];
#pragma unroll
            for (int y = 0; y < 2; ++y)
                bf[y] = *(const bf16x8*)&Bs[(wn + y*16 + mrow)*32 + kq*8];
#pragma unroll
            for (int a = 0; a < 4; ++a)
#pragma unroll
                for (int b = 0; b < 2; ++b)
                    c[a][b] = __builtin_amdgcn_mfma_f32_16x16x32_bf16(af[a], bf[b], c[a][b], 0, 0, 0);
            __syncthreads();
        }
        float* outp = part + (long)sk*(128*NPAD);
#pragma unroll
        for (int a = 0; a < 4; ++a)
#pragma unroll
            for (int b = 0; b < 2; ++b){
                int r0 = wm + a*16 + (lane >> 4)*4;
                int col = n_base + wn + b*16 + (lane & 15);
#pragma unroll
                for (int reg = 0; reg < 4; ++reg)
                    outp[(long)(r0+reg)*NPAD + col] = c[a][b][reg];
            }
    } else {
        // ---- GLU + LayerNorm (256 threads, 8 dims/thread) ----
        float* redA = (float*)U;          // 4 floats
        float* redB = (float*)(U + 16);   // 4 floats
        int b = bid - 512;
        int d0 = tid*8;
        const float* base = C0 + (long)b*4096;
        float4 a0 = *(const float4*)(base + d0);
        float4 a1 = *(const float4*)(base + d0 + 4);
        float4 g0 = *(const float4*)(base + 2048 + d0);
        float4 g1 = *(const float4*)(base + 2048 + d0 + 4);
#pragma unroll
        for (int s = 0; s < 8; ++s){
            const float* zb = zp + (long)s*524288 + (long)b*4096;
            float4 z0 = *(const float4*)(zb + d0);
            float4 z1 = *(const float4*)(zb + d0 + 4);
            float4 y0 = *(const float4*)(zb + 2048 + d0);
            float4 y1 = *(const float4*)(zb + 2048 + d0 + 4);
            a0.x+=z0.x; a0.y+=z0.y; a0.z+=z0.z; a0.w+=z0.w;
            a1.x+=z1.x; a1.y+=z1.y; a1.z+=z1.z; a1.w+=z1.w;
            g0.x+=y0.x; g0.y+=y0.y; g0.z+=y0.z; g0.w+=y0.w;
            g1.x+=y1.x; g1.y+=y1.y; g1.z+=y1.z; g1.w+=y1.w;
        }
        float v[8];
        v[0]=a0.x*sigm(g0.x); v[1]=a0.y*sigm(g0.y); v[2]=a0.z*sigm(g0.z); v[3]=a0.w*sigm(g0.w);
        v[4]=a1.x*sigm(g1.x); v[5]=a1.y*sigm(g1.y); v[6]=a1.z*sigm(g1.z); v[7]=a1.w*sigm(g1.w);
        float s1 = 0.f, s2 = 0.f;
#pragma unroll
        for (int i = 0; i < 8; ++i){ s1 += v[i]; s2 += v[i]*v[i]; }
#pragma unroll
        for (int off = 32; off; off >>= 1){
            s1 += __shfl_down(s1, off);
            s2 += __shfl_down(s2, off);
        }
        int w = tid >> 6;
        if ((tid & 63) == 0){ redA[w] = s1; redB[w] = s2; }
        __syncthreads();
        if (tid == 0){
            float sa = redA[0]+redA[1]+redA[2]+redA[3];
            float sb = redB[0]+redB[1]+redB[2]+redB[3];
            float mu = sa*(1.f/2048.f);
            float var = sb*(1.f/2048.f) - mu*mu;
            redA[0] = mu;
            redB[0] = rsqrtf(var + 1e-5f);
        }
        __syncthreads();
        float mu = redA[0], inv = redB[0];
        float4 lg0 = *(const float4*)(lng + d0);
        float4 lg1 = *(const float4*)(lng + d0 + 4);
        float4 lb0 = *(const float4*)(lnb + d0);
        float4 lb1 = *(const float4*)(lnb + d0 + 4);
        float gg[8] = {lg0.x,lg0.y,lg0.z,lg0.w,lg1.x,lg1.y,lg1.z,lg1.w};
        float bb[8] = {lb0.x,lb0.y,lb0.z,lb0.w,lb1.x,lb1.y,lb1.z,lb1.w};
        long obase = ((long)slot*DMODEL + d0)*BB + b;
#pragma unroll
        for (int i = 0; i < 8; ++i){
            float st = (v[i]-mu)*inv*gg[i] + bb[i];
            unsigned short h = f2bf(st);
            trh[obase + (long)i*BB] = h;
            trl[obase + (long)i*BB] = f2bf(st - bf2f(h));
        }
    }
}

// D2(t): reduce(t-1) [blocks 0..127] ∥ trace(t) [blocks 128..2175]; 256 threads
__global__ __launch_bounds__(256) void d2_red_trace_k(
    const float* __restrict__ part, const float* __restrict__ outb, float* __restrict__ dout,
    const unsigned short* __restrict__ trh, const unsigned short* __restrict__ trl,
    const unsigned short* __restrict__ w1bf,
    const float* __restrict__ b1, const float* __restrict__ w2t, const float* __restrict__ b2,
    float* __restrict__ act, unsigned short* __restrict__ aTh, unsigned short* __restrict__ aTl,
    int t){
    __shared__ __align__(16) char U[45824];
    int tid = threadIdx.x;
    int bid = blockIdx.x;
    if (bid < 128){
        if (t <= 0) return;
        reduce_row(part, outb, dout, (float*)U, bid, t - 1, tid);
    } else {
        // ---- trace_proc(t): per-d block ----
        int d = bid - 128;
        unsigned short* Ah   = (unsigned short*)U;             // 128*40*2 = 10240 B
        unsigned short* Al   = (unsigned short*)(U + 10240);   // 10240 B
        unsigned short* Bbuf = (unsigned short*)(U + 20480);   // 4096*2 = 8192 B
        float* hh  = (float*)(U + 28672);                      // 128*33*4 = 16896 B
        float* w2s = (float*)(U + 45568);                      // 256 B

        for (int i = tid; i < MEMN*64; i += 256){
            int m = i >> 6, bp = i & 63;
            int phys = t + 1 + m; if (phys >= MEMN) phys -= MEMN; if (phys >= MEMN) phys -= MEMN;
            long gaddr = ((long)phys*DMODEL + d)*BB + bp*2;
            ushort2 vh = *(const ushort2*)(trh + gaddr);
            ushort2 vl = *(const ushort2*)(trl + gaddr);
            Ah[(bp*2+0)*40 + m] = vh.x; Ah[(bp*2+1)*40 + m] = vh.y;
            Al[(bp*2+0)*40 + m] = vl.x; Al[(bp*2+1)*40 + m] = vl.y;
        }
        for (int i = tid; i < 7*128; i += 256){
            int m = MEMN + (i >> 7), b = i & 127;
            Ah[b*40 + m] = 0; Al[b*40 + m] = 0;
        }
        {
            const uint4* src = (const uint4*)(w1bf + (long)d*4096);
            uint4* dst = (uint4*)Bbuf;
            for (int i = tid; i < 512; i += 256) dst[i] = src[i];
        }
        if (tid < 64) w2s[tid] = w2t[(long)d*64 + tid];
        __syncthreads();

        int wid = tid >> 6, lane = tid & 63;
        int mrow = lane & 15, kq = lane >> 4;
        bf16x8 ahf[2], alf[2], bhf[4], blf[4];
#pragma unroll
        for (int bt = 0; bt < 2; ++bt){
            int r = (wid*2 + bt)*16 + mrow;
            ahf[bt] = *(const bf16x8*)&Ah[r*40 + kq*8];
            alf[bt] = *(const bf16x8*)&Al[r*40 + kq*8];
        }
#pragma unroll
        for (int ht = 0; ht < 4; ++ht){
            int r = ht*16 + mrow;
            bhf[ht] = *(const bf16x8*)&Bbuf[r*32 + kq*8];
            blf[ht] = *(const bf16x8*)&Bbuf[2048 + r*32 + kq*8];
        }
        f32x4 c[2][4];
#pragma unroll
        for (int bt = 0; bt < 2; ++bt)
#pragma unroll
            for (int ht = 0; ht < 4; ++ht){
                c[bt][ht] = (f32x4){0.f,0.f,0.f,0.f};
                c[bt][ht] = __builtin_amdgcn_mfma_f32_16x16x32_bf16(ahf[bt], bhf[ht], c[bt][ht], 0, 0, 0);
                c[bt][ht] = __builtin_amdgcn_mfma_f32_16x16x32_bf16(alf[bt], bhf[ht], c[bt][ht], 0, 0, 0);
                c[bt][ht] = __builtin_amdgcn_mfma_f32_16x16x32_bf16(ahf[bt], blf[ht], c[bt][ht], 0, 0, 0);
            }
        int quad = lane >> 4;
#pragma unroll
        for (int bt = 0; bt < 2; ++bt){
            int bb0 = (wid*2 + bt)*16 + quad*4;
#pragma unroll
            for (int ht = 0; ht < 2; ++ht){
                int h = ht*16 + (lane & 15);
                float ba = b1[(long)d*64 + h];
                float bg = b1[(long)d*64 + 32 + h];
#pragma unroll
                for (int reg = 0; reg < 4; ++reg){
                    float a = c[bt][ht][reg] + ba;
                    float g = c[bt][ht+2][reg] + bg;
                    hh[(bb0+reg)*33 + h] = a * sigm(g);
                }
            }
        }
        __syncthreads();
        if (tid < 128){
            int bb = tid;
            float o0 = b2[(long)d*2+0], o1 = b2[(long)d*2+1];
#pragma unroll
            for (int h = 0; h < 32; ++h){
                float hv = hh[bb*33 + h];
                o0 += hv * w2s[h*2+0];
                o1 += hv * w2s[h*2+1];
            }
            float a = o0 * sigm(o1);
            act[(long)d*BB + bb] = a;
            unsigned short h16 = f2bf(a);
            aTh[(long)bb*DMODEL + d] = h16;
            aTl[(long)bb*DMODEL + d] = f2bf(a - bf2f(h16));
        }
    }
}

// D3(t): syn(t+1) [blocks 0..511] ∥ pairwise(t) [blocks 512..1039]; 256 threads
__global__ __launch_bounds__(256) void d3_syn_pair_k(
    const unsigned short* __restrict__ Ah, const unsigned short* __restrict__ Al,
    const unsigned short* __restrict__ Bh, const unsigned short* __restrict__ Bl,
    float* __restrict__ zpart,
    const float* __restrict__ act, const float* __restrict__ decay,
    const int* __restrict__ il, const int* __restrict__ ir,
    const int* __restrict__ rowOf, const int* __restrict__ rowstart,
    float* __restrict__ alpha, unsigned short* __restrict__ syncb, int t){
    __shared__ __align__(16) char U[24576];
    int tid = threadIdx.x;
    int bid = blockIdx.x;
    if (bid < 512){
        // ---- syn(t+1): zpart[s][128][4096-slice] = actT @ swT^T (hi/lo bf16) ----
        if (t >= ITERS-1) return;
        unsigned short* As_h = (unsigned short*)U;             // 8192 B
        unsigned short* As_l = (unsigned short*)(U + 8192);    // 8192 B
        unsigned short* Bs_h = (unsigned short*)(U + 16384);   // 4096 B
        unsigned short* Bs_l = (unsigned short*)(U + 20480);   // 4096 B
        int wid = tid >> 6, lane = tid & 63;
        int wm = (wid & 1)*64, wn = (wid >> 1)*32;
        int mrow = lane & 15, kq = lane >> 4;
        int srow = tid >> 2;
        int ksg  = (tid & 3)*8;
        int nb = bid & 63;
        int s  = bid >> 6;

        f32x4 c[4][2];
#pragma unroll
        for (int a = 0; a < 4; ++a)
#pragma unroll
            for (int b = 0; b < 2; ++b) c[a][b] = (f32x4){0.f,0.f,0.f,0.f};

        long koff0 = (long)s*256 + ksg;
        const unsigned short* gAh1 = Ah + (long)srow*DMODEL      + koff0;
        const unsigned short* gAh2 = Ah + (long)(srow+64)*DMODEL + koff0;
        const unsigned short* gAl1 = Al + (long)srow*DMODEL      + koff0;
        const unsigned short* gAl2 = Al + (long)(srow+64)*DMODEL + koff0;
        const unsigned short* gBh  = Bh + (long)(nb*64+srow)*DMODEL + koff0;
        const unsigned short* gBl  = Bl + (long)(nb*64+srow)*DMODEL + koff0;
        unsigned short* lAh1 = As_h + wid*512;
        unsigned short* lAh2 = As_h + 2048 + wid*512;
        unsigned short* lAl1 = As_l + wid*512;
        unsigned short* lAl2 = As_l + 2048 + wid*512;
        unsigned short* lBh  = Bs_h + wid*512;
        unsigned short* lBl  = Bs_l + wid*512;

        for (int ks = 0; ks < 8; ++ks){
            int o = ks*32;
            gload16(gAh1 + o, lAh1);
            gload16(gAh2 + o, lAh2);
            gload16(gAl1 + o, lAl1);
            gload16(gAl2 + o, lAl2);
            gload16(gBh  + o, lBh);
            gload16(gBl  + o, lBl);
            __syncthreads();
            bf16x8 ah[4], al[4], bh[2], bl[2];
#pragma unroll
            for (int x = 0; x < 4; ++x){
                ah[x] = *(const bf16x8*)&As_h[(wm + x*16 + mrow)*32 + kq*8];
                al[x] = *(const bf16x8*)&As_l[(wm + x*16 + mrow)*32 + kq*8];
            }
#pragma unroll
            for (int y = 0; y < 2; ++y){
                bh[y] = *(const bf16x8*)&Bs_h[(wn + y*16 + mrow)*32 + kq*8];
                bl[y] = *(const bf16x8*)&Bs_l[(wn + y*16 + mrow)*32 + kq*8];
            }
#pragma unroll
            for (int a = 0; a < 4; ++a)
#pragma unroll
                for (int b = 0; b < 2; ++b){
                    c[a][b] = __builtin_amdgcn_mfma_f32_16x16x32_bf16(ah[a], bh[b], c[a][b], 0, 0, 0);
                    c[a][b] = __builtin_amdgcn_mfma_f32_16x16x32_bf16(al[a], bh[b], c[a][b], 0, 0, 0);
                    c[a][b] = __builtin_amdgcn_mfma_f32_16x16x32_bf16(ah[a], bl[b], c[a][b], 0, 0, 0);
                }
            __syncthreads();
        }
        float* outp = zpart + (long)s*(BB*4096);
#pragma unroll
        for (int a = 0; a < 4; ++a)
#pragma unroll
            for (int b = 0; b < 2; ++b){
                int r0 = wm + a*16 + (lane >> 4)*4;
                int col = nb*64 + wn + b*16 + (lane & 15);
#pragma unroll
                for (int reg = 0; reg < 4; ++reg)
                    outp[(long)(r0+reg)*4096 + col] = c[a][b][reg];
            }
    } else {
        // ---- pairwise(t) + alpha update + sync write ----
        if (t < 0) return;
        int idx = bid - 512;         // [0, 528)
        int xx = idx % 132;
        int bg = idx / 132;
        int k = xx*256 + tid;
        int blo = bg*32, bhi = blo + 32;
        if (k >= SYNCN){
            if (k < KPAD)
                for (int b = blo; b < bhi; ++b) syncb[(long)b*KPAD + k] = 0;
            return;
        }
        int i = rowOf[k];
        int j = i + (k - rowstart[i]);
        float cc = fminf(fmaxf(decay[k], 0.f), 15.f);
        float r = __expf(-cc);
        float bet;
        if (cc < 1e-30f) bet = (float)(t + 2);
        else {
            float e1 = expm1f(-cc);
            float et = expm1f(-cc*(float)(t+1));
            bet = 1.f + et + et/e1;
        }
        float rs = rsqrtf(bet);
        const float* aL = act + (long)il[i]*BB;
        const float* aR = act + (long)ir[j]*BB;
        for (int b = blo; b < bhi; ++b){
            float pp = aL[b]*aR[b];
            float al = r*alpha[(long)b*SYNCN + k] + pp;
            alpha[(long)b*SYNCN + k] = al;
            syncb[(long)b*KPAD + k] = f2bf(al*rs);
        }
    }
}

// standalone out_gemm for the final iteration's projection
__global__ __launch_bounds__(256) void out_gemm_k(const unsigned short* __restrict__ Abf,
    const unsigned short* __restrict__ Bbf, float* __restrict__ part){
    int n_base = blockIdx.x*64;
    int sk = blockIdx.y;
    int tid = threadIdx.x;
    int wid = tid >> 6, lane = tid & 63;
    int wm = (wid & 1)*64, wn = (wid >> 1)*32;
    long k_base = (long)sk*KCH;
    __shared__ __align__(16) unsigned short As[128*32];
    __shared__ __align__(16) unsigned short Bs[64*32];
    f32x4 c[4][2];
#pragma unroll
    for (int a = 0; a < 4; ++a)
#pragma unroll
        for (int b = 0; b < 2; ++b) c[a][b] = (f32x4){0.f,0.f,0.f,0.f};

    int mrow = lane & 15, kq = lane >> 4;
    int srow = tid >> 2;
    int ksg  = (tid & 3)*8;
    const unsigned short* gA1 = Abf + (long)srow*KPAD      + k_base + ksg;
    const unsigned short* gA2 = Abf + (long)(srow+64)*KPAD + k_base + ksg;
    const unsigned short* gB  = Bbf + (long)(n_base+srow)*KPAD + k_base + ksg;
    unsigned short* lA1 = As + wid*512;
    unsigned short* lA2 = As + 2048 + wid*512;
    unsigned short* lB  = Bs + wid*512;

    for (int ks = 0; ks < KCH/32; ++ks){
        int o = ks*32;
        gload16(gA1 + o, lA1);
        gload16(gA2 + o, lA2);
        gload16(gB  + o, lB);
        __syncthreads();
        bf16x8 af[4], bf[2];
#pragma unroll
        for (int x = 0; x < 4; ++x)
            af[x] = *(const bf16x8*)&As[(wm + x*16 + mrow)*32 + kq*8];
#pragma unroll
        for (int y = 0; y < 2; ++y)
            bf[y] = *(const bf16x8*)&Bs[(wn + y*16 + mrow)*32 + kq*8];
#pragma unroll
        for (int a = 0; a < 4; ++a)
#pragma unroll
            for (int b = 0; b < 2; ++b)
                c[a][b] = __builtin_amdgcn_mfma_f32_16x16x32_bf16(af[a], bf[b], c[a][b], 0, 0, 0);
        __syncthreads();
    }
    float* outp = part + (long)sk*(128*NPAD);
#pragma unroll
    for (int a = 0; a < 4; ++a)
#pragma unroll
        for (int b = 0; b < 2; ++b){
            int r0 = wm + a*16 + (lane >> 4)*4;
            int col = n_base + wn + b*16 + (lane & 15);
#pragma unroll
            for (int reg = 0; reg < 4; ++reg)
                outp[(long)(r0+reg)*NPAD + col] = c[a][b][reg];
        }
}

// standalone reduce for the last iteration (t = ITERS-1)
__global__ __launch_bounds__(256) void reduce_final_k(const float* __restrict__ part,
    const float* __restrict__ outb, float* __restrict__ dout){
    __shared__ float red[8];
    reduce_row(part, outb, dout, red, blockIdx.x, ITERS-1, threadIdx.x);
}

// ---------------- host ----------------

extern "C" void kernel_launch(void* const* d_in, const int* in_sizes, int n_in,
                              void* d_out, int out_size, void* d_ws, size_t ws_size,
                              hipStream_t stream){
    const float* x      = (const float*)d_in[0];
    const float* syn_w  = (const float*)d_in[1];
    const float* syn_b  = (const float*)d_in[2];
    const float* ln_g   = (const float*)d_in[3];
    const float* ln_b   = (const float*)d_in[4];
    const float* tp_w1  = (const float*)d_in[5];
    const float* tp_b1  = (const float*)d_in[6];
    const float* tp_w2  = (const float*)d_in[7];
    const float* tp_b2  = (const float*)d_in[8];
    const float* sas    = (const float*)d_in[9];
    const float* strc   = (const float*)d_in[10];
    const float* decay  = (const float*)d_in[11];
    const float* out_w  = (const float*)d_in[12];
    const float* out_b  = (const float*)d_in[13];
    const int*   il     = (const int*)d_in[14];
    const int*   ir     = (const int*)d_in[15];
    float* dout = (float*)d_out;

    char* ws = (char*)d_ws;
    size_t off = 0;
    auto alloc = [&](size_t bytes)->void*{
        void* p = ws + off;
        off += (bytes + 255) & ~(size_t)255;
        return p;
    };
    unsigned short* trh = (unsigned short*)alloc((size_t)MEMN*DMODEL*BB*2);  // 13.1 MB [m][d][b]
    unsigned short* trl = (unsigned short*)alloc((size_t)MEMN*DMODEL*BB*2);  // 13.1 MB
    float* act     = (float*)alloc((size_t)DMODEL*BB*4);          // 1 MB     [d][b]
    float* C0      = (float*)alloc((size_t)BB*4096*4);            // 2.1 MB
    float* xt      = (float*)alloc((size_t)DIN*BB*4);             // 0.26 MB  [k][b]
    float* w2t     = (float*)alloc((size_t)DMODEL*64*4);          // 0.52 MB  [d][h*2+o]
    unsigned short* w1bf = (unsigned short*)alloc((size_t)DMODEL*4096*2);    // 16.8 MB [d][plane][h*32+m]
    float* alpha   = (float*)alloc((size_t)BB*SYNCN*4);           // 16.8 MB
    unsigned short* syncb = (unsigned short*)alloc((size_t)BB*KPAD*2);   // 8.65 MB [b][k]
    unsigned short* wbt   = (unsigned short*)alloc((size_t)NPAD*KPAD*2); // 69.2 MB [n][k]
    // part: out_gemm split-K partials (32 splits). Aliased as w1t during init only.
    float* part    = (float*)alloc((size_t)NSPLIT*BB*NPAD*4);     // 16.8 MB
    float* w1t     = part;
    // zpart: syn split-K partials (8 splits); must not alias part.
    float* zpart   = (float*)alloc((size_t)8*BB*4096*4);          // 16.8 MB
    unsigned short* swT_h = (unsigned short*)alloc((size_t)4096*DMODEL*2); // 16.8 MB [n][k]
    unsigned short* swT_l = (unsigned short*)alloc((size_t)4096*DMODEL*2); // 16.8 MB
    unsigned short* aT_h  = (unsigned short*)alloc((size_t)BB*DMODEL*2);   // 0.52 MB [b][d]
    unsigned short* aT_l  = (unsigned short*)alloc((size_t)BB*DMODEL*2);   // 0.52 MB
    int* rowOf    = (int*)alloc((size_t)SYNCN*4);
    int* rowstart = (int*)alloc((size_t)NSY*4);
    (void)ws_size; (void)in_sizes; (void)n_in; (void)out_size;

    // ---- once-per-launch precompute ----
    init_trace_k<<<8192, 256, 0, stream>>>(strc, trh, trl);
    init_act_k<<<1024, 256, 0, stream>>>(sas, act);
    init_alpha_k<<<256, 256, 0, stream>>>(sas, il, ir, alpha);
    init_rowmap_k<<<256, 256, 0, stream>>>(rowOf, rowstart);
    transpose_f32_k<<<dim3(32, 25), 256, 0, stream>>>(tp_w1, w1t, 1600, 2048);
    w1bf_prep_k<<<2048, 256, 0, stream>>>(w1t, w1bf);
    transpose_f32_k<<<dim3(32, 1),  256, 0, stream>>>(tp_w2, w2t, 64, 2048);
    transpose_f32_k<<<dim3(8, 2),   256, 0, stream>>>(x, xt, 128, 512);
    wbf_transpose_k<<<dim3(KPAD/64, 16), 256, 0, stream>>>(out_w, wbt);
    swt_convert_k<<<dim3(32, 64), 256, 0, stream>>>(syn_w, swT_h, swT_l);
    gemm_syn_k<<<64, 256, 0, stream>>>(xt, syn_w, syn_b, C0);
    act_convert_k<<<dim3(32, 2), 256, 0, stream>>>(act, aT_h, aT_l);

    // ---- prologue: syn(0) (D3 with t=-1: pairwise skipped) ----
    d3_syn_pair_k<<<1040, 256, 0, stream>>>(aT_h, aT_l, swT_h, swT_l, zpart,
                                            act, decay, il, ir, rowOf, rowstart,
                                            alpha, syncb, -1);

    // ---- 24 iterations, 3 dispatches each ----
    for (int t = 0; t < ITERS; ++t){
        d1_out_glu_k<<<640, 256, 0, stream>>>(syncb, wbt, part,
                                              C0, zpart, ln_g, ln_b, trh, trl,
                                              t % MEMN, t > 0);
        d2_red_trace_k<<<2176, 256, 0, stream>>>(part, out_b, dout,
                                                 trh, trl, w1bf, tp_b1, w2t, tp_b2,
                                                 act, aT_h, aT_l, t);
        d3_syn_pair_k<<<1040, 256, 0, stream>>>(aT_h, aT_l, swT_h, swT_l, zpart,
                                                act, decay, il, ir, rowOf, rowstart,
                                                alpha, syncb, t);
    }
    // ---- tail: out(23) + reduce(23) ----
    out_gemm_k<<<dim3(16, NSPLIT), 256, 0, stream>>>(syncb, wbt, part);
    reduce_final_k<<<128, 256, 0, stream>>>(part, out_b, dout);
}